// Round 17
// baseline (1188.937 us; speedup 1.0000x reference)
//
#include <hip/hip_runtime.h>
#include <math.h>

#define EPSV 1e-4f
#define NSWEEP 10
#define NRT (99 * NSWEEP)
#define SKIPTH 4e-8f
#define TAUBRK 5e-3f

// ---------- 16-lane all-reduce sum on the VALU (DPP), no LDS pipe ----------
template <int CTRL>
__device__ __forceinline__ float dppadd(float x) {
  int y = __builtin_amdgcn_update_dpp(0, __float_as_int(x), CTRL, 0xF, 0xF, false);
  return x + __int_as_float(y);
}
__device__ __forceinline__ float sum16(float x) {
  x = dppadd<0xB1>(x);   // quad_perm [1,0,3,2]  == xor 1
  x = dppadd<0x4E>(x);   // quad_perm [2,3,0,1]  == xor 2
  x = dppadd<0x124>(x);  // row_ror:4
  x = dppadd<0x128>(x);  // row_ror:8
  return x;
}

// ---------- Kernel A: W = W1 @ W2 (400x200 @ 200x100 -> 400x100) ----------
__global__ __launch_bounds__(256) void kA(const float* __restrict__ W1,
                                          const float* __restrict__ W2,
                                          float* __restrict__ W) {
  int e = blockIdx.x * 256 + threadIdx.x;
  if (e >= 400 * 100) return;
  int i = e / 100, j = e - (e / 100) * 100;
  float s = 0.f;
#pragma unroll 4
  for (int k = 0; k < 200; ++k) s += W1[i * 200 + k] * W2[k * 100 + j];
  W[e] = s;
}

// ---------- Kernel B: Y[b] = x[b] @ W : 40x100 tile/block, 4x4 reg tiles, b128 LDS ----
__global__ __launch_bounds__(256) void kB(const float* __restrict__ x,
                                          const float* __restrict__ W,
                                          float* __restrict__ Y) {
  __shared__ __align__(16) float xsT[40 * 40];   // [kk][row]
  __shared__ __align__(16) float ws[40 * 104];   // [kk][col]
  const int b = blockIdx.y, rt = blockIdx.x;
  const int tid = threadIdx.x;
  const int r0 = tid / 25, c0 = tid - (tid / 25) * 25;  // valid when tid<250
  const float* xb = x + (size_t)b * 160000 + (size_t)rt * 40 * 400;
  float acc[4][4];
#pragma unroll
  for (int a = 0; a < 4; ++a) acc[a][0] = acc[a][1] = acc[a][2] = acc[a][3] = 0.f;
  for (int k0 = 0; k0 < 400; k0 += 40) {
    for (int e = tid; e < 1600; e += 256) {
      int r = e / 40, kk = e - r * 40;
      xsT[kk * 40 + r] = xb[r * 400 + k0 + kk];
    }
    for (int e = tid; e < 4000; e += 256) {
      int kk = e / 100, j = e - kk * 100;
      ws[kk * 104 + j] = W[(k0 + kk) * 100 + j];
    }
    __syncthreads();
    if (tid < 250) {
      for (int kk = 0; kk < 40; ++kk) {
        float4 x4 = *(const float4*)&xsT[kk * 40 + 4 * r0];
        float4 w4 = *(const float4*)&ws[kk * 104 + 4 * c0];
        const float xv[4] = {x4.x, x4.y, x4.z, x4.w};
        const float wv[4] = {w4.x, w4.y, w4.z, w4.w};
#pragma unroll
        for (int a = 0; a < 4; ++a)
#pragma unroll
          for (int c = 0; c < 4; ++c) acc[a][c] += xv[a] * wv[c];
      }
    }
    __syncthreads();
  }
  if (tid < 250) {
    float* Yb = Y + (size_t)b * 40000 + ((size_t)rt * 40 + 4 * r0) * 100 + 4 * c0;
#pragma unroll
    for (int a = 0; a < 4; ++a) {
      float4 v = make_float4(acc[a][0], acc[a][1], acc[a][2], acc[a][3]);
      *(float4*)(Yb + a * 100) = v;
    }
  }
}

// flat triu index (n=100) -> row (one-off use in symmetrize)
__device__ __forceinline__ int triu_row(int e) {
  int i = (int)((201.0f - sqrtf(40401.0f - 8.0f * (float)e)) * 0.5f);
  if (i < 0) i = 0;
  if (i > 99) i = 99;
  while (i > 0 && (201 * i - i * i) > 2 * e) --i;
  while ((201 * (i + 1) - (i + 1) * (i + 1)) <= 2 * e) ++i;
  return i;
}

// ---------- Kernel C: M = W^T Y_b ; logm via ONE-SIDED Jacobi (dataflow sync) ----------
__global__ __launch_bounds__(1024) void kC(const float* __restrict__ W,
                                           const float* __restrict__ Y,
                                           const float* __restrict__ Wc,
                                           const float* __restrict__ bcv,
                                           float* __restrict__ out) {
  __shared__ float B[10000];      // column-major: column p at B + p*100
  __shared__ float stage[8320];   // GEMM staging; later Hf[5050]
  __shared__ float nrm[100];      // maintained squared column norms
  __shared__ float sfin[100];
  __shared__ float red[16][12];
  __shared__ float tstat[50];
  __shared__ int rotflag[50];
  __shared__ int ver[100];        // per-column round counters (dataflow sync)
  __shared__ int brk;

  const int b = blockIdx.x, tid = threadIdx.x;
  const int g = tid >> 4, lane = tid & 15;  // 64 groups of 16 (wave-aligned)
  const int r0 = tid / 25, c0 = tid - (tid / 25) * 25;

  // ---- M = W^T @ Y_b  into B : 4x4 register tiles, b128 LDS reads ----
  {
    float* Wst = stage;          // [40][104]
    float* Yst = stage + 4160;   // [40][104]
    const float* Yb = Y + (size_t)b * 40000;
    float acc[4][4];
#pragma unroll
    for (int a = 0; a < 4; ++a) acc[a][0] = acc[a][1] = acc[a][2] = acc[a][3] = 0.f;
    for (int k0 = 0; k0 < 400; k0 += 40) {
      for (int e = tid; e < 4000; e += 1024) {
        int kk = e / 100, j = e - kk * 100;
        Wst[kk * 104 + j] = W[(k0 + kk) * 100 + j];
        Yst[kk * 104 + j] = Yb[(k0 + kk) * 100 + j];
      }
      __syncthreads();
      if (tid < 625) {
        for (int kk = 0; kk < 40; ++kk) {
          float4 w4 = *(const float4*)&Wst[kk * 104 + 4 * r0];
          float4 y4 = *(const float4*)&Yst[kk * 104 + 4 * c0];
          const float wv[4] = {w4.x, w4.y, w4.z, w4.w};
          const float yv[4] = {y4.x, y4.y, y4.z, y4.w};
#pragma unroll
          for (int a = 0; a < 4; ++a)
#pragma unroll
            for (int c = 0; c < 4; ++c) acc[a][c] += wv[a] * yv[c];
        }
      }
      __syncthreads();
    }
    if (tid < 625) {
#pragma unroll
      for (int a = 0; a < 4; ++a) {
        float4 v = make_float4(acc[a][0], acc[a][1], acc[a][2], acc[a][3]);
        *(float4*)&B[(4 * r0 + a) * 100 + 4 * c0] = v;
      }
    }
  }
  if (tid < 50) { rotflag[tid] = 0; tstat[tid] = 0.f; }
  if (tid < 100) ver[tid] = 0;
  __syncthreads();
  // symmetrize both triangles
  for (int e = tid; e < 5050; e += 1024) {
    int i = triu_row(e);
    int j = i + (e - ((201 * i - i * i) >> 1));
    float av = 0.5f * (B[i * 100 + j] + B[j * 100 + i]);
    B[i * 100 + j] = av;
    B[j * 100 + i] = av;
  }
  __syncthreads();
  // initial squared norms (group g covers columns g, g+64)
  for (int col = g; col < 100; col += 64) {
    const float* bp = B + col * 100;
    float4 a4 = *(const float4*)(bp + 4 * lane);
    float n = a4.x * a4.x + a4.y * a4.y + a4.z * a4.z + a4.w * a4.w;
    if (lane < 9) {
      float4 a8 = *(const float4*)(bp + 64 + 4 * lane);
      n += a8.x * a8.x + a8.y * a8.y + a8.z * a8.z + a8.w * a8.w;
    }
    n = sum16(n);
    if (lane == 0) nrm[col] = n;
  }
  __syncthreads();

  // ---- one-sided cyclic Jacobi: dataflow sync via per-column version flags ----
  // Invariant: ver[c] == number of completed rounds for column c. Each column
  // has exactly one owner group per round, so waiting for ver>=r then bumping
  // to r+1 after our writes drain is race-free and deadlock-free.
  int p, q;
  if (g == 0) { p = 99; q = 0; }
  else { p = g; q = 99 - g; }
  int pp = p * 100, qq = q * 100;
  float tacc = 0.f;
  int any = 0;
  volatile int* vv = ver;

  for (int r = 0; r < NRT; ++r) {
    const int rr = r % 99;
    if (g < 50) {
      // spin until both columns have completed round r-1
      while (vv[p] < r || vv[q] < r) { __builtin_amdgcn_s_sleep(1); }
      float* bp = B + pp;
      float* bq = B + qq;
      float4 a4 = *(const float4*)(bp + 4 * lane);
      float4 b4 = *(const float4*)(bq + 4 * lane);
      float4 a8 = make_float4(0.f, 0.f, 0.f, 0.f), b8 = a8;
      float d = a4.x * b4.x + a4.y * b4.y + a4.z * b4.z + a4.w * b4.w;
      if (lane < 9) {
        a8 = *(const float4*)(bp + 64 + 4 * lane);
        b8 = *(const float4*)(bq + 64 + 4 * lane);
        d += a8.x * b8.x + a8.y * b8.y + a8.z * b8.z + a8.w * b8.w;
      }
      d = sum16(d);  // VALU DPP all-reduce
      float pn = nrm[p], qn = nrm[q];
      if (d * d > SKIPTH * pn * qn + 1e-30f) {  // group-uniform branch
        float tau = (qn - pn) / (2.f * d);
        float t = copysignf(1.f, tau) / (fabsf(tau) + sqrtf(1.f + tau * tau));
        float c = 1.f / sqrtf(1.f + t * t);
        float s = t * c;
        float4 n4, m4;
        n4.x = c * a4.x - s * b4.x; n4.y = c * a4.y - s * b4.y;
        n4.z = c * a4.z - s * b4.z; n4.w = c * a4.w - s * b4.w;
        m4.x = s * a4.x + c * b4.x; m4.y = s * a4.y + c * b4.y;
        m4.z = s * a4.z + c * b4.z; m4.w = s * a4.w + c * b4.w;
        *(float4*)(bp + 4 * lane) = n4;
        *(float4*)(bq + 4 * lane) = m4;
        if (lane < 9) {
          n4.x = c * a8.x - s * b8.x; n4.y = c * a8.y - s * b8.y;
          n4.z = c * a8.z - s * b8.z; n4.w = c * a8.w - s * b8.w;
          m4.x = s * a8.x + c * b8.x; m4.y = s * a8.y + c * b8.y;
          m4.z = s * a8.z + c * b8.z; m4.w = s * a8.w + c * b8.w;
          *(float4*)(bp + 64 + 4 * lane) = n4;
          *(float4*)(bq + 64 + 4 * lane) = m4;
        }
        tacc += t * t;
        any = 1;
        if (lane == 0) {
          nrm[p] = pn - t * d;   // exact Jacobi diagonal update
          nrm[q] = qn + t * d;
        }
      }
      // drain this wave's LDS writes, then publish round completion
      asm volatile("s_waitcnt lgkmcnt(0)" ::: "memory");
      if (lane == 0) { vv[p] = r + 1; vv[q] = r + 1; }
    }
    // advance schedule incrementally (matches rr+1)
    ++q; qq += 100; if (q == 99) { q = 0; qq = 0; }
    if (g != 0) { ++p; pp += 100; if (p == 99) { p = 0; pp = 0; } }
    if (rr == 98) {  // sweep end: collect stats (this barrier re-syncs the block)
      if (g < 50 && lane == 0) { rotflag[g] = any; tstat[g] = tacc; }
      any = 0; tacc = 0.f;
      __syncthreads();
      if (tid < 64) {
        int v = (tid < 50) ? rotflag[tid] : 0;
        float tv = (tid < 50) ? tstat[tid] : 0.f;
#pragma unroll
        for (int off = 32; off > 0; off >>= 1) {
          v += __shfl_xor(v, off);
          tv += __shfl_xor(tv, off);
        }
        if (tid == 0) brk = (v == 0 || tv < TAUBRK) ? 1 : 0;
      }
      __syncthreads();
      if (brk) break;
    }
  }
  __syncthreads();  // all rounds' writes visible before reading B below

  // ---- exact final scales: sfin[p] = log(max(||b_p||,EPSV)) / ||b_p||^2 ----
  for (int col = g; col < 100; col += 64) {
    const float* bp = B + col * 100;
    float4 a4 = *(const float4*)(bp + 4 * lane);
    float n = a4.x * a4.x + a4.y * a4.y + a4.z * a4.z + a4.w * a4.w;
    if (lane < 9) {
      float4 a8 = *(const float4*)(bp + 64 + 4 * lane);
      n += a8.x * a8.x + a8.y * a8.y + a8.z * a8.z + a8.w * a8.w;
    }
    n = sum16(n);
    if (lane == 0) sfin[col] = logf(fmaxf(sqrtf(n), EPSV)) / n;
  }
  __syncthreads();

  // ---- Hf (triu flat) = sum_p sfin[p] * b_p b_p^T : 4x4 tiles, b128 reads ----
  float* Hf = stage;
  if (tid < 625) {
    float hacc[4][4];
#pragma unroll
    for (int a = 0; a < 4; ++a) hacc[a][0] = hacc[a][1] = hacc[a][2] = hacc[a][3] = 0.f;
    for (int pc = 0; pc < 100; ++pc) {
      const float* vr = B + pc * 100;
      float l = sfin[pc];
      float4 vi4 = *(const float4*)&vr[4 * r0];
      float4 vj4 = *(const float4*)&vr[4 * c0];
      const float vi[4] = {l * vi4.x, l * vi4.y, l * vi4.z, l * vi4.w};
      const float vj[4] = {vj4.x, vj4.y, vj4.z, vj4.w};
#pragma unroll
      for (int a = 0; a < 4; ++a)
#pragma unroll
        for (int c = 0; c < 4; ++c) hacc[a][c] += vi[a] * vj[c];
    }
#pragma unroll
    for (int a = 0; a < 4; ++a) {
      int i = 4 * r0 + a;
#pragma unroll
      for (int c = 0; c < 4; ++c) {
        int j = 4 * c0 + c;
        if (i <= j) Hf[((201 * i - i * i) >> 1) + (j - i)] = hacc[a][c];
      }
    }
  }
  __syncthreads();  // uniform: all threads reach

  // ---- classifier ----
  float accc[10];
#pragma unroll
  for (int c = 0; c < 10; ++c) accc[c] = 0.f;
  for (int e = tid; e < 5050; e += 1024) {
    float h = Hf[e];
#pragma unroll
    for (int c = 0; c < 10; ++c) accc[c] += h * Wc[c * 5050 + e];
  }
  const int lane64 = tid & 63, wv = tid >> 6;
#pragma unroll
  for (int c = 0; c < 10; ++c) {
    float v = accc[c];
#pragma unroll
    for (int off = 32; off > 0; off >>= 1) v += __shfl_down(v, off);
    if (lane64 == 0) red[wv][c] = v;
  }
  __syncthreads();
  if (tid < 10) {
    float s = bcv[tid];
#pragma unroll
    for (int w = 0; w < 16; ++w) s += red[w][tid];
    out[b * 10 + tid] = s;
  }
}

extern "C" void kernel_launch(void* const* d_in, const int* in_sizes, int n_in,
                              void* d_out, int out_size, void* d_ws, size_t ws_size,
                              hipStream_t stream) {
  const float* x = (const float*)d_in[0];
  const float* W1 = (const float*)d_in[1];
  const float* W2 = (const float*)d_in[2];
  const float* Wc = (const float*)d_in[3];
  const float* bc = (const float*)d_in[4];
  float* out = (float*)d_out;

  float* W = (float*)d_ws;        // 400*100 floats
  float* Y = W + 40000;           // 256*400*100 floats (~41 MB)

  kA<<<157, 256, 0, stream>>>(W1, W2, W);
  kB<<<dim3(10, 256), 256, 0, stream>>>(x, W, Y);
  kC<<<256, 1024, 0, stream>>>(W, Y, Wc, bc, out);
}

// Round 18
// 1072.398 us; speedup vs baseline: 1.1087x; 1.1087x over previous
//
#include <hip/hip_runtime.h>
#include <math.h>

#define EPSV 1e-4f
#define NSWEEP 10
#define NRT (99 * NSWEEP)
#define SKIPTH 4e-8f
#define TAUBRK 5e-3f

// ---------- 16-lane all-reduce sum on the VALU (DPP), no LDS pipe ----------
template <int CTRL>
__device__ __forceinline__ float dppadd(float x) {
  int y = __builtin_amdgcn_update_dpp(0, __float_as_int(x), CTRL, 0xF, 0xF, false);
  return x + __int_as_float(y);
}
__device__ __forceinline__ float sum16(float x) {
  x = dppadd<0xB1>(x);   // quad_perm [1,0,3,2]  == xor 1
  x = dppadd<0x4E>(x);   // quad_perm [2,3,0,1]  == xor 2
  x = dppadd<0x124>(x);  // row_ror:4
  x = dppadd<0x128>(x);  // row_ror:8
  return x;
}

// ---------- Kernel A: W = W1 @ W2 (400x200 @ 200x100 -> 400x100) ----------
__global__ __launch_bounds__(256) void kA(const float* __restrict__ W1,
                                          const float* __restrict__ W2,
                                          float* __restrict__ W) {
  int e = blockIdx.x * 256 + threadIdx.x;
  if (e >= 400 * 100) return;
  int i = e / 100, j = e - (e / 100) * 100;
  float s = 0.f;
#pragma unroll 4
  for (int k = 0; k < 200; ++k) s += W1[i * 200 + k] * W2[k * 100 + j];
  W[e] = s;
}

// ---------- Kernel B: Y[b] = x[b] @ W : 40x100 tile/block, 4x4 reg tiles, b128 LDS ----
__global__ __launch_bounds__(256) void kB(const float* __restrict__ x,
                                          const float* __restrict__ W,
                                          float* __restrict__ Y) {
  __shared__ __align__(16) float xsT[40 * 40];   // [kk][row], pitch 40 (160B, 16B-aligned)
  __shared__ __align__(16) float ws[40 * 104];   // [kk][col], pitch 104 (416B, 16B-aligned)
  const int b = blockIdx.y, rt = blockIdx.x;     // rt in [0,10): rows rt*40..rt*40+39
  const int tid = threadIdx.x;
  const int r0 = tid / 25, c0 = tid - (tid / 25) * 25;  // valid when tid<250
  const float* xb = x + (size_t)b * 160000 + (size_t)rt * 40 * 400;
  float acc[4][4];
#pragma unroll
  for (int a = 0; a < 4; ++a) acc[a][0] = acc[a][1] = acc[a][2] = acc[a][3] = 0.f;
  for (int k0 = 0; k0 < 400; k0 += 40) {
    // stage x^T (transposed) and W
    for (int e = tid; e < 1600; e += 256) {
      int r = e / 40, kk = e - r * 40;
      xsT[kk * 40 + r] = xb[r * 400 + k0 + kk];
    }
    for (int e = tid; e < 4000; e += 256) {
      int kk = e / 100, j = e - kk * 100;
      ws[kk * 104 + j] = W[(k0 + kk) * 100 + j];
    }
    __syncthreads();
    if (tid < 250) {
      for (int kk = 0; kk < 40; ++kk) {
        float4 x4 = *(const float4*)&xsT[kk * 40 + 4 * r0];
        float4 w4 = *(const float4*)&ws[kk * 104 + 4 * c0];
        const float xv[4] = {x4.x, x4.y, x4.z, x4.w};
        const float wv[4] = {w4.x, w4.y, w4.z, w4.w};
#pragma unroll
        for (int a = 0; a < 4; ++a)
#pragma unroll
          for (int c = 0; c < 4; ++c) acc[a][c] += xv[a] * wv[c];
      }
    }
    __syncthreads();
  }
  if (tid < 250) {
    float* Yb = Y + (size_t)b * 40000 + ((size_t)rt * 40 + 4 * r0) * 100 + 4 * c0;
#pragma unroll
    for (int a = 0; a < 4; ++a) {
      float4 v = make_float4(acc[a][0], acc[a][1], acc[a][2], acc[a][3]);
      *(float4*)(Yb + a * 100) = v;
    }
  }
}

// flat triu index (n=100) -> row (one-off use in symmetrize)
__device__ __forceinline__ int triu_row(int e) {
  int i = (int)((201.0f - sqrtf(40401.0f - 8.0f * (float)e)) * 0.5f);
  if (i < 0) i = 0;
  if (i > 99) i = 99;
  while (i > 0 && (201 * i - i * i) > 2 * e) --i;
  while ((201 * (i + 1) - (i + 1) * (i + 1)) <= 2 * e) ++i;
  return i;
}

// ---------- Kernel C: M = W^T Y_b ; logm via ONE-SIDED Jacobi ; classifier ----------
__global__ __launch_bounds__(1024) void kC(const float* __restrict__ W,
                                           const float* __restrict__ Y,
                                           const float* __restrict__ Wc,
                                           const float* __restrict__ bcv,
                                           float* __restrict__ out) {
  __shared__ float B[10000];      // column-major: column p at B + p*100
  __shared__ float stage[8320];   // GEMM staging; later Hf[5050]
  __shared__ float nrm[100];      // maintained squared column norms
  __shared__ float sfin[100];
  __shared__ float red[16][12];
  __shared__ float tstat[50];
  __shared__ int rotflag[50];
  __shared__ int brk;

  const int b = blockIdx.x, tid = threadIdx.x;
  const int g = tid >> 4, lane = tid & 15;  // 64 groups of 16 (wave-aligned)
  // 4x4 tile mapping for GEMM / H phases (625 active threads)
  const int r0 = tid / 25, c0 = tid - (tid / 25) * 25;

  // ---- M = W^T @ Y_b  into B : 4x4 register tiles, b128 LDS reads ----
  {
    float* Wst = stage;          // [40][104]
    float* Yst = stage + 4160;   // [40][104]
    const float* Yb = Y + (size_t)b * 40000;
    float acc[4][4];
#pragma unroll
    for (int a = 0; a < 4; ++a) acc[a][0] = acc[a][1] = acc[a][2] = acc[a][3] = 0.f;
    for (int k0 = 0; k0 < 400; k0 += 40) {
      for (int e = tid; e < 4000; e += 1024) {
        int kk = e / 100, j = e - kk * 100;
        Wst[kk * 104 + j] = W[(k0 + kk) * 100 + j];
        Yst[kk * 104 + j] = Yb[(k0 + kk) * 100 + j];
      }
      __syncthreads();        // uniform: all threads reach
      if (tid < 625) {
        for (int kk = 0; kk < 40; ++kk) {
          float4 w4 = *(const float4*)&Wst[kk * 104 + 4 * r0];
          float4 y4 = *(const float4*)&Yst[kk * 104 + 4 * c0];
          const float wv[4] = {w4.x, w4.y, w4.z, w4.w};
          const float yv[4] = {y4.x, y4.y, y4.z, y4.w};
#pragma unroll
          for (int a = 0; a < 4; ++a)
#pragma unroll
            for (int c = 0; c < 4; ++c) acc[a][c] += wv[a] * yv[c];
        }
      }
      __syncthreads();        // uniform: all threads reach
    }
    if (tid < 625) {
#pragma unroll
      for (int a = 0; a < 4; ++a) {
        float4 v = make_float4(acc[a][0], acc[a][1], acc[a][2], acc[a][3]);
        *(float4*)&B[(4 * r0 + a) * 100 + 4 * c0] = v;
      }
    }
  }
  if (tid < 50) { rotflag[tid] = 0; tstat[tid] = 0.f; }
  __syncthreads();
  // symmetrize both triangles
  for (int e = tid; e < 5050; e += 1024) {
    int i = triu_row(e);
    int j = i + (e - ((201 * i - i * i) >> 1));
    float av = 0.5f * (B[i * 100 + j] + B[j * 100 + i]);
    B[i * 100 + j] = av;
    B[j * 100 + i] = av;
  }
  __syncthreads();
  // initial squared norms (group g covers columns g, g+64)
  for (int col = g; col < 100; col += 64) {
    const float* bp = B + col * 100;
    float4 a4 = *(const float4*)(bp + 4 * lane);
    float n = a4.x * a4.x + a4.y * a4.y + a4.z * a4.z + a4.w * a4.w;
    if (lane < 9) {
      float4 a8 = *(const float4*)(bp + 64 + 4 * lane);
      n += a8.x * a8.x + a8.y * a8.y + a8.z * a8.z + a8.w * a8.w;
    }
    n = sum16(n);
    if (lane == 0) nrm[col] = n;
  }
  __syncthreads();

  // ---- one-sided cyclic Jacobi: fused dot+rotate, incremental schedule ----
  int p, q;
  if (g == 0) { p = 99; q = 0; }
  else { p = g; q = 99 - g; }
  int pp = p * 100, qq = q * 100;
  float tacc = 0.f;
  int any = 0;

  for (int r = 0; r < NRT; ++r) {
    const int rr = r % 99;
    if (g < 50) {
      float* bp = B + pp;
      float* bq = B + qq;
      float4 a4 = *(const float4*)(bp + 4 * lane);
      float4 b4 = *(const float4*)(bq + 4 * lane);
      float4 a8 = make_float4(0.f, 0.f, 0.f, 0.f), b8 = a8;
      float d = a4.x * b4.x + a4.y * b4.y + a4.z * b4.z + a4.w * b4.w;
      if (lane < 9) {
        a8 = *(const float4*)(bp + 64 + 4 * lane);
        b8 = *(const float4*)(bq + 64 + 4 * lane);
        d += a8.x * b8.x + a8.y * b8.y + a8.z * b8.z + a8.w * b8.w;
      }
      d = sum16(d);  // VALU DPP all-reduce
      float pn = nrm[p], qn = nrm[q];
      if (d * d > SKIPTH * pn * qn + 1e-30f) {  // group-uniform branch
        float tau = (qn - pn) / (2.f * d);
        float t = copysignf(1.f, tau) / (fabsf(tau) + sqrtf(1.f + tau * tau));
        float c = 1.f / sqrtf(1.f + t * t);
        float s = t * c;
        float4 n4, m4;
        n4.x = c * a4.x - s * b4.x; n4.y = c * a4.y - s * b4.y;
        n4.z = c * a4.z - s * b4.z; n4.w = c * a4.w - s * b4.w;
        m4.x = s * a4.x + c * b4.x; m4.y = s * a4.y + c * b4.y;
        m4.z = s * a4.z + c * b4.z; m4.w = s * a4.w + c * b4.w;
        *(float4*)(bp + 4 * lane) = n4;
        *(float4*)(bq + 4 * lane) = m4;
        if (lane < 9) {
          n4.x = c * a8.x - s * b8.x; n4.y = c * a8.y - s * b8.y;
          n4.z = c * a8.z - s * b8.z; n4.w = c * a8.w - s * b8.w;
          m4.x = s * a8.x + c * b8.x; m4.y = s * a8.y + c * b8.y;
          m4.z = s * a8.z + c * b8.z; m4.w = s * a8.w + c * b8.w;
          *(float4*)(bp + 64 + 4 * lane) = n4;
          *(float4*)(bq + 64 + 4 * lane) = m4;
        }
        tacc += t * t;
        any = 1;
        if (lane == 0) {
          nrm[p] = pn - t * d;   // exact Jacobi diagonal update
          nrm[q] = qn + t * d;
        }
      }
    }
    __syncthreads();
    // advance schedule incrementally (matches rr+1)
    ++q; qq += 100; if (q == 99) { q = 0; qq = 0; }
    if (g != 0) { ++p; pp += 100; if (p == 99) { p = 0; pp = 0; } }
    if (rr == 98) {  // sweep end: reduce rot flags + sum of t^2 (uniform branch)
      if (g < 50 && lane == 0) { rotflag[g] = any; tstat[g] = tacc; }
      any = 0; tacc = 0.f;
      __syncthreads();
      if (tid < 64) {
        int v = (tid < 50) ? rotflag[tid] : 0;
        float tv = (tid < 50) ? tstat[tid] : 0.f;
#pragma unroll
        for (int off = 32; off > 0; off >>= 1) {
          v += __shfl_xor(v, off);
          tv += __shfl_xor(tv, off);
        }
        if (tid == 0) brk = (v == 0 || tv < TAUBRK) ? 1 : 0;
      }
      __syncthreads();
      if (brk) break;
    }
  }

  // ---- exact final scales: sfin[p] = log(max(||b_p||,EPSV)) / ||b_p||^2 ----
  for (int col = g; col < 100; col += 64) {
    const float* bp = B + col * 100;
    float4 a4 = *(const float4*)(bp + 4 * lane);
    float n = a4.x * a4.x + a4.y * a4.y + a4.z * a4.z + a4.w * a4.w;
    if (lane < 9) {
      float4 a8 = *(const float4*)(bp + 64 + 4 * lane);
      n += a8.x * a8.x + a8.y * a8.y + a8.z * a8.z + a8.w * a8.w;
    }
    n = sum16(n);
    if (lane == 0) sfin[col] = logf(fmaxf(sqrtf(n), EPSV)) / n;
  }
  __syncthreads();

  // ---- Hf (triu flat) = sum_p sfin[p] * b_p b_p^T : 4x4 tiles, b128 reads ----
  // NO barrier inside divergent flow: Hf aliases stage (dead), B read-only here.
  float* Hf = stage;
  if (tid < 625) {
    float hacc[4][4];
#pragma unroll
    for (int a = 0; a < 4; ++a) hacc[a][0] = hacc[a][1] = hacc[a][2] = hacc[a][3] = 0.f;
    for (int pc = 0; pc < 100; ++pc) {
      const float* vr = B + pc * 100;
      float l = sfin[pc];
      float4 vi4 = *(const float4*)&vr[4 * r0];
      float4 vj4 = *(const float4*)&vr[4 * c0];
      const float vi[4] = {l * vi4.x, l * vi4.y, l * vi4.z, l * vi4.w};
      const float vj[4] = {vj4.x, vj4.y, vj4.z, vj4.w};
#pragma unroll
      for (int a = 0; a < 4; ++a)
#pragma unroll
        for (int c = 0; c < 4; ++c) hacc[a][c] += vi[a] * vj[c];
    }
#pragma unroll
    for (int a = 0; a < 4; ++a) {
      int i = 4 * r0 + a;
#pragma unroll
      for (int c = 0; c < 4; ++c) {
        int j = 4 * c0 + c;
        if (i <= j) Hf[((201 * i - i * i) >> 1) + (j - i)] = hacc[a][c];
      }
    }
  }
  __syncthreads();  // uniform: all threads reach

  // ---- classifier ----
  float accc[10];
#pragma unroll
  for (int c = 0; c < 10; ++c) accc[c] = 0.f;
  for (int e = tid; e < 5050; e += 1024) {
    float h = Hf[e];
#pragma unroll
    for (int c = 0; c < 10; ++c) accc[c] += h * Wc[c * 5050 + e];
  }
  const int lane64 = tid & 63, wv = tid >> 6;
#pragma unroll
  for (int c = 0; c < 10; ++c) {
    float v = accc[c];
#pragma unroll
    for (int off = 32; off > 0; off >>= 1) v += __shfl_down(v, off);
    if (lane64 == 0) red[wv][c] = v;
  }
  __syncthreads();
  if (tid < 10) {
    float s = bcv[tid];
#pragma unroll
    for (int w = 0; w < 16; ++w) s += red[w][tid];
    out[b * 10 + tid] = s;
  }
}

extern "C" void kernel_launch(void* const* d_in, const int* in_sizes, int n_in,
                              void* d_out, int out_size, void* d_ws, size_t ws_size,
                              hipStream_t stream) {
  const float* x = (const float*)d_in[0];
  const float* W1 = (const float*)d_in[1];
  const float* W2 = (const float*)d_in[2];
  const float* Wc = (const float*)d_in[3];
  const float* bc = (const float*)d_in[4];
  float* out = (float*)d_out;

  float* W = (float*)d_ws;        // 400*100 floats
  float* Y = W + 40000;           // 256*400*100 floats (~41 MB)

  kA<<<157, 256, 0, stream>>>(W1, W2, W);
  kB<<<dim3(10, 256), 256, 0, stream>>>(x, W, Y);
  kC<<<256, 1024, 0, stream>>>(W, Y, Wc, bc, out);
}